// Round 7
// baseline (87.304 us; speedup 1.0000x reference)
//
#include <hip/hip_runtime.h>

#define NB   8192
#define NJ   14
#define NC   18
#define PIX  196            // 14*14
#define CHE  (NC * PIX)     // 3528 floats per batch
#define CHE4 (CHE / 4)      // 882 float4 per batch
#define BPB  4              // batches per block (1 wave = 1 batch)
#define NBLK (NB / BPB)     // 2048 blocks
#define GSTR 16             // padded row stride of g table

#define WSUM_INV 0.398943491f   // 1 / sum(exp(-k^2/2), k=-4..4)

__global__ __launch_bounds__(256) void mse_kernel(
    const float* __restrict__ h, const float* __restrict__ t,
    const int* __restrict__ v, float2* __restrict__ partials,
    int* __restrict__ counter, float* __restrict__ out)
{
    __shared__ float  gs[15 * GSTR];       // g[p][r]; rows 0..13 table, row 14 zeros
    __shared__ float  gmn[14], gmx[14];
    __shared__ float  st[BPB * 28];
    __shared__ int    sv[BPB * 28];
    __shared__ float4 list[BPB * NC];      // per-wave segment [w*NC, w*NC+cnt)
    __shared__ float  fmat[BPB * 4 * PIX]; // raw f for np>=2 group channels
    __shared__ float  wvs[BPB];
    __shared__ float  wred[BPB];
    __shared__ int    sdone;

    const int tid = threadIdx.x;
    const int b0  = blockIdx.x * BPB;
    const int w   = tid >> 6, lane = tid & 63;

    // ---- phase 0: raw t/v loads + padded g table ----
    if (tid < BPB * 28)               st[tid] = t[b0 * 28 + tid];
    else if (tid < 2 * BPB * 28)      sv[tid - BPB * 28] = v[b0 * 28 + (tid - BPB * 28)];
    if (tid < 15 * GSTR) {
        int p = tid >> 4, r = tid & 15;
        float val = 0.f;
        if (p < 14 && r < 14) {
            const float wl[9] = {0.00033546262f, 0.011108997f, 0.13533528f, 0.60653066f,
                                 1.0f, 0.60653066f, 0.13533528f, 0.011108997f, 0.00033546262f};
            float acc = 0.f;
            #pragma unroll
            for (int k = 0; k < 9; k++) {
                int m  = r + k - 4;
                int sm = m < 0 ? (-m - 1) : (m > 13 ? 27 - m : m);  // symmetric reflect
                if (sm == p) acc += wl[k];
            }
            val = acc * WSUM_INV;
        }
        gs[tid] = val;
    }
    __syncthreads();

    if (tid < 14) {
        float mn = 1e30f, mx = -1e30f;
        #pragma unroll
        for (int r = 0; r < 14; r++) { float x = gs[tid * GSTR + r]; mn = fminf(mn, x); mx = fmaxf(mx, x); }
        gmn[tid] = mn; gmx[tid] = mx;
    }
    __syncthreads();

    // ---- phase 1: per-wave (= per-batch) channel metadata ----
    int xi = 0, yi = 0, vis = 0;
    if (lane < NJ) {
        float fx = st[w * 28 + 2 * lane];       // t[...,0] -> x (col)
        float fy = st[w * 28 + 2 * lane + 1];   // t[...,1] -> y (row)
        xi = (int)(fx * 14.0f); xi = xi < 0 ? 0 : (xi > 13 ? 13 : xi);
        yi = (int)(fy * 14.0f); yi = yi < 0 ? 0 : (yi > 13 ? 13 : yi);
        vis = (sv[w * 28 + 2 * lane] == 1);
    }
    float nmn_c = 0.f, inv_c = 0.f;
    int   pos_c = 0, act_c = 0, np_c = 0;
    if (lane < NJ && vis) {
        float mn = gmn[yi] * gmn[xi], mx = gmx[yi] * gmx[xi];   // separable, g >= 0
        float den = mx - mn; if (den == 0.f) den = 1.f;
        inv_c = 1.f / den; nmn_c = -mn * inv_c; act_c = 1; np_c = 1;
        pos_c = yi | (xi << 4);
    }
    for (int gi = 0; gi < 4; gi++) {
        int j0 = 3 * gi;
        int ys[3], xs[3], vs_[3];
        #pragma unroll
        for (int q = 0; q < 3; q++) {
            ys[q]  = __shfl(yi,  j0 + q);
            xs[q]  = __shfl(xi,  j0 + q);
            vs_[q] = __shfl(vis, j0 + q);
        }
        int packed = 0, np = 0;
        #pragma unroll
        for (int q = 0; q < 3; q++) {
            if (vs_[q]) {
                bool dup = false;
                for (int s = 0; s < np; s++) {
                    int yq = (packed >> (8 * s)) & 15, xq = (packed >> (8 * s + 4)) & 15;
                    if (yq == ys[q] && xq == xs[q]) dup = true;
                }
                if (!dup) { packed |= (ys[q] << (8 * np)) | (xs[q] << (8 * np + 4)); np++; }
            }
        }
        float mn = 0.f, mx = 0.f;
        if (np == 1) {
            int y0p = packed & 15, x0p = (packed >> 4) & 15;
            mn = gmn[y0p] * gmn[x0p]; mx = gmx[y0p] * gmx[x0p];
        } else if (np >= 2) {           // wave-uniform: full eval; store f to fmat
            int slot = w * 4 + gi;
            float lmn = 1e30f, lmx = -1e30f;
            for (int e = lane; e < PIX; e += 64) {
                int rr = e / 14, cc = e - 14 * rr;
                float f = 0.f;
                for (int q = 0; q < np; q++) {
                    int yq = (packed >> (8 * q)) & 15, xq = (packed >> (8 * q + 4)) & 15;
                    f += gs[yq * GSTR + rr] * gs[xq * GSTR + cc];
                }
                fmat[slot * PIX + e] = f;
                lmn = fminf(lmn, f); lmx = fmaxf(lmx, f);
            }
            #pragma unroll
            for (int m = 1; m < 64; m <<= 1) {
                lmn = fminf(lmn, __shfl_xor(lmn, m));
                lmx = fmaxf(lmx, __shfl_xor(lmx, m));
            }
            mn = lmn; mx = lmx;
        }
        if (lane == NJ + gi && np > 0) {
            float den = mx - mn; if (den == 0.f) den = 1.f;
            inv_c = 1.f / den; nmn_c = -mn * inv_c; act_c = 1; np_c = np;
            pos_c = (np == 1) ? ((packed & 15) | (((packed >> 4) & 15) << 4))
                              : (w * 4 + gi);   // slot index for fmat path
        }
    }
    {
        int vval = (lane < 28) ? sv[w * 28 + lane] : 0;
        unsigned long long bal = __ballot(vval == 1);
        if (lane == 0) wvs[w] = (float)__popcll(bal);
    }
    // partition this wave's entries: [0,c1) single-pos, [c1,c1+cX) multi-pos
    unsigned long long b1 = __ballot(act_c && np_c == 1);
    unsigned long long bX = __ballot(act_c && np_c >= 2);
    const int c1 = __popcll(b1);
    const int cX = __popcll(bX);
    unsigned long long below = (1ull << lane) - 1ull;
    if (act_c) {
        int idx = (np_c == 1) ? __popcll(b1 & below) : c1 + __popcll(bX & below);
        float4 e;
        e.x = nmn_c; e.y = inv_c;
        e.z = __int_as_float(pos_c);
        e.w = __int_as_float(w * CHE4 + lane * 49);   // channel == lane
        list[w * NC + idx] = e;
    }
    // no barrier: each wave reads only its own list/fmat segment (in-order LDS)

    // ---- phase 2: stream h; static chunk-of-7, all loads issued up-front ----
    const float4* hb4 = (const float4*)(h + (size_t)b0 * CHE);
    const int  lane49 = lane < 48 ? lane : 48;
    const bool lv     = (lane < 49);
    const int  pix0   = lane49 * 4;
    const int  rr0    = pix0 / 14;
    const int  cc0    = pix0 - 14 * rr0;       // even: 0..12
    const bool wrap   = (cc0 == 12);
    const int  ccB    = wrap ? 0 : cc0 + 2;
    const int  lbase  = w * NC;
    float acc = 0.f;

    auto chunk7 = [&](int base, int cnt) {
        float4 mv[7], hv[7];
        #pragma unroll
        for (int j = 0; j < 7; j++) {
            int ee = base + j;
            mv[j] = list[lbase + (ee < cnt ? ee : cnt - 1)];
        }
        #pragma unroll
        for (int j = 0; j < 7; j++)
            hv[j] = hb4[__float_as_int(mv[j].w) + lane49];   // 7 independent loads
        #pragma unroll
        for (int j = 0; j < 7; j++) {
            int   p   = __float_as_int(mv[j].z);
            float nmn = mv[j].x, inv = mv[j].y;
            int y = p & 15, x = (p >> 4) & 15;
            const float* ry = &gs[y * GSTR];
            const float* rx = &gs[x * GSTR];
            float wy0  = ry[rr0], wy1 = ry[rr0 + 1];   // ds_read2
            float wxA0 = rx[cc0], wxA1 = rx[cc0 + 1];  // ds_read2
            float wxB0 = rx[ccB], wxB1 = rx[ccB + 1];  // ds_read2
            float wyC  = wrap ? wy1 : wy0;
            float d0 = hv[j].x - fmaf(wy0 * wxA0, inv, nmn);
            float d1 = hv[j].y - fmaf(wy0 * wxA1, inv, nmn);
            float d2 = hv[j].z - fmaf(wyC * wxB0, inv, nmn);
            float d3 = hv[j].w - fmaf(wyC * wxB1, inv, nmn);
            float s  = fmaf(d0, d0, fmaf(d1, d1, fmaf(d2, d2, d3 * d3)));
            acc += ((base + j < cnt) && lv) ? s : 0.f;
        }
    };
    if (c1 > 0) {                 // wave-uniform branches; c1 <= 14 => <= 2 chunks
        chunk7(0, c1);
        if (c1 > 7) chunk7(7, c1);
    }

    const int cT = c1 + cX;
    for (int e = c1; e < cT; e += 2) {         // slow path: np >= 2, f from fmat
        float4 mv[2], hv[2], f4[2];
        int    vld[2];
        #pragma unroll
        for (int j = 0; j < 2; j++) {
            int ee = e + j;
            vld[j] = (ee < cT);
            mv[j]  = list[lbase + (vld[j] ? ee : cT - 1)];
        }
        #pragma unroll
        for (int j = 0; j < 2; j++) {
            hv[j] = hb4[__float_as_int(mv[j].w) + lane49];
            const float4* fp = (const float4*)&fmat[__float_as_int(mv[j].z) * PIX];
            f4[j] = fp[lane49];
        }
        #pragma unroll
        for (int j = 0; j < 2; j++) {
            float nmn = mv[j].x, inv = mv[j].y;
            float d0 = hv[j].x - fmaf(f4[j].x, inv, nmn);
            float d1 = hv[j].y - fmaf(f4[j].y, inv, nmn);
            float d2 = hv[j].z - fmaf(f4[j].z, inv, nmn);
            float d3 = hv[j].w - fmaf(f4[j].w, inv, nmn);
            float s  = fmaf(d0, d0, fmaf(d1, d1, fmaf(d2, d2, d3 * d3)));
            acc += (vld[j] && lv) ? s : 0.f;
        }
    }

    // ---- block reduce + last-block-done finalize ----
    #pragma unroll
    for (int off = 32; off > 0; off >>= 1) acc += __shfl_down(acc, off);
    if (lane == 0) wred[w] = acc;
    __syncthreads();
    if (tid == 0) {
        float2 pr;
        pr.x = wred[0] + wred[1] + wred[2] + wred[3];
        pr.y = wvs[0] + wvs[1] + wvs[2] + wvs[3];
        partials[blockIdx.x] = pr;
        __threadfence();                      // release partials device-wide
        int prev = atomicAdd(counter, 1);
        sdone = (prev == NBLK - 1);
    }
    __syncthreads();
    if (sdone) {                              // exactly one block; fixed-order sum
        __threadfence();                      // acquire other blocks' partials
        float s = 0.f, vs = 0.f;
        #pragma unroll
        for (int i = 0; i < NBLK / 256; i++) {
            float2 p = partials[tid + i * 256];
            s += p.x; vs += p.y;
        }
        #pragma unroll
        for (int off = 32; off > 0; off >>= 1) {
            s  += __shfl_down(s, off);
            vs += __shfl_down(vs, off);
        }
        if (lane == 0) { wred[w] = s; wvs[w] = vs; }
        __syncthreads();
        if (tid == 0) {
            float stot = wred[0] + wred[1] + wred[2] + wred[3];
            float vtot = wvs[0] + wvs[1] + wvs[2] + wvs[3];
            out[0] = stot / (vtot * 0.5f);
        }
    }
}

extern "C" void kernel_launch(void* const* d_in, const int* in_sizes, int n_in,
                              void* d_out, int out_size, void* d_ws, size_t ws_size,
                              hipStream_t stream) {
    // inputs: 0=os (UNUSED), 1=h [B,18,14,14] f32, 2=t [B,14,2] f32, 3=v [B,14,2] i32
    const float* h = (const float*)d_in[1];
    const float* t = (const float*)d_in[2];
    const int*   v = (const int*)d_in[3];
    float2* partials = (float2*)d_ws;                               // NBLK float2
    int*    counter  = (int*)((char*)d_ws + NBLK * sizeof(float2)); // 1 int

    hipMemsetAsync(counter, 0, sizeof(int), stream);  // deterministic per-call reset
    mse_kernel<<<NBLK, 256, 0, stream>>>(h, t, v, partials, counter, (float*)d_out);
}

// Round 8
// 27.051 us; speedup vs baseline: 3.2274x; 3.2274x over previous
//
#include <hip/hip_runtime.h>

#define NB   8192
#define NJ   14
#define NC   18
#define PIX  196            // 14*14
#define CHE  (NC * PIX)     // 3528 floats per batch
#define CHE4 (CHE / 4)      // 882 float4 per batch
#define BPB  4              // batches per block (1 wave = 1 batch)
#define NBLK (NB / BPB)     // 2048 blocks
#define GSTR 16             // padded row stride of g table
#define ZROW 14             // zero row (unused position slots)

#define WSUM_INV 0.398943491f   // 1 / sum(exp(-k^2/2), k=-4..4)

__global__ __launch_bounds__(256, 4) void mse_partial_kernel(
    const float* __restrict__ h, const float* __restrict__ t,
    const int* __restrict__ v, float2* __restrict__ partials)
{
    __shared__ float  gs[15 * GSTR];   // g[p][r]; rows 0..13 table, row 14 zeros
    __shared__ float  gmn[14], gmx[14];
    __shared__ float  st[BPB * 28];
    __shared__ int    sv[BPB * 28];
    __shared__ float4 list[BPB * NC];  // per-wave segment [w*NC, w*NC+cnt)
    __shared__ float  wvs[BPB];
    __shared__ float  wred[BPB];

    const int tid = threadIdx.x;
    const int b0  = blockIdx.x * BPB;
    const int w   = tid >> 6, lane = tid & 63;

    // ---- phase 0: raw t/v loads + padded g table ----
    if (tid < BPB * 28)               st[tid] = t[b0 * 28 + tid];
    else if (tid < 2 * BPB * 28)      sv[tid - BPB * 28] = v[b0 * 28 + (tid - BPB * 28)];
    if (tid < 15 * GSTR) {
        int p = tid >> 4, r = tid & 15;
        float val = 0.f;
        if (p < 14 && r < 14) {
            const float wl[9] = {0.00033546262f, 0.011108997f, 0.13533528f, 0.60653066f,
                                 1.0f, 0.60653066f, 0.13533528f, 0.011108997f, 0.00033546262f};
            float acc = 0.f;
            #pragma unroll
            for (int k = 0; k < 9; k++) {
                int m  = r + k - 4;
                int sm = m < 0 ? (-m - 1) : (m > 13 ? 27 - m : m);  // symmetric reflect
                if (sm == p) acc += wl[k];
            }
            val = acc * WSUM_INV;
        }
        gs[tid] = val;
    }
    __syncthreads();

    if (tid < 14) {
        float mn = 1e30f, mx = -1e30f;
        #pragma unroll
        for (int r = 0; r < 14; r++) { float x = gs[tid * GSTR + r]; mn = fminf(mn, x); mx = fmaxf(mx, x); }
        gmn[tid] = mn; gmx[tid] = mx;
    }
    __syncthreads();

    // per-lane element coords for the 196-pixel group eval (hoisted out of gi loop)
    int rr_[4], cc_[4], vld_[4];
    #pragma unroll
    for (int q = 0; q < 4; q++) {
        int e = lane + 64 * q;
        vld_[q] = (e < PIX);
        int ee = vld_[q] ? e : PIX - 1;
        rr_[q] = ee / 14; cc_[q] = ee - 14 * rr_[q];
    }

    // ---- phase 1: per-wave (= per-batch) channel metadata ----
    int xi = 0, yi = 0, vis = 0;
    if (lane < NJ) {
        float fx = st[w * 28 + 2 * lane];       // t[...,0] -> x (col)
        float fy = st[w * 28 + 2 * lane + 1];   // t[...,1] -> y (row)
        xi = (int)(fx * 14.0f); xi = xi < 0 ? 0 : (xi > 13 ? 13 : xi);
        yi = (int)(fy * 14.0f); yi = yi < 0 ? 0 : (yi > 13 ? 13 : yi);
        vis = (sv[w * 28 + 2 * lane] == 1);
    }
    const int code = (vis << 8) | (xi << 4) | yi;   // 9-bit joint descriptor

    float nmn_c = 0.f, inv_c = 0.f;
    int   pos_c = 0, act_c = 0, np_c = 0;
    if (lane < NJ && vis) {
        float mn = gmn[yi] * gmn[xi], mx = gmx[yi] * gmx[xi];   // separable, g >= 0
        float den = mx - mn; if (den == 0.f) den = 1.f;
        inv_c = 1.f / den; nmn_c = -mn * inv_c; act_c = 1; np_c = 1;
        pos_c = yi | (xi << 4);
    }
    for (int gi = 0; gi < 4; gi++) {
        int c0 = __shfl(code, 3 * gi);
        int c1_ = __shfl(code, 3 * gi + 1);
        int c2 = __shfl(code, 3 * gi + 2);
        int packed = 0, np = 0;
        if (c0 & 0x100) { packed = c0 & 0xFF; np = 1; }
        if (c1_ & 0x100) {
            int pc = c1_ & 0xFF;
            bool dup = (np > 0) && ((packed & 0xFF) == pc);
            if (!dup) { packed |= pc << (8 * np); np++; }
        }
        if (c2 & 0x100) {
            int pc = c2 & 0xFF;
            bool dup = false;
            for (int s = 0; s < np; s++) if (((packed >> (8 * s)) & 0xFF) == pc) dup = true;
            if (!dup) { packed |= pc << (8 * np); np++; }
        }
        int pp = packed;                 // pad unused slots with zero-row
        if (np < 2) pp |= ZROW << 8;
        if (np < 3) pp |= ZROW << 16;

        float mn = 0.f, mx = 0.f;
        if (np == 1) {
            int y = packed & 15, x = (packed >> 4) & 15;
            mn = gmn[y] * gmn[x]; mx = gmx[y] * gmx[x];
        } else if (np >= 2) {            // wave-uniform: exact 196-pixel min/max
            float lmn = 1e30f, lmx = -1e30f;
            #pragma unroll
            for (int q2 = 0; q2 < 4; q2++) {
                float f = 0.f;
                #pragma unroll
                for (int s = 0; s < 3; s++) {
                    int y = (pp >> (8 * s)) & 15, x = (pp >> (8 * s + 4)) & 15;
                    f += gs[y * GSTR + rr_[q2]] * gs[x * GSTR + cc_[q2]];
                }
                lmn = fminf(lmn, vld_[q2] ? f : 1e30f);
                lmx = fmaxf(lmx, vld_[q2] ? f : -1e30f);
            }
            #pragma unroll
            for (int m = 1; m < 64; m <<= 1) {
                lmn = fminf(lmn, __shfl_xor(lmn, m));
                lmx = fmaxf(lmx, __shfl_xor(lmx, m));
            }
            mn = lmn; mx = lmx;
        }
        if (lane == NJ + gi && np > 0) {
            float den = mx - mn; if (den == 0.f) den = 1.f;
            inv_c = 1.f / den; nmn_c = -mn * inv_c; act_c = 1; np_c = np;
            pos_c = (np == 1) ? (packed & 0xFF) : pp;
        }
    }
    {
        int vval = (lane < 28) ? sv[w * 28 + lane] : 0;
        unsigned long long bal = __ballot(vval == 1);
        if (lane == 0) wvs[w] = (float)__popcll(bal);
    }
    // partition this wave's entries: [0,c1) single-pos, [c1,c1+cX) multi-pos
    unsigned long long b1 = __ballot(act_c && np_c == 1);
    unsigned long long bX = __ballot(act_c && np_c >= 2);
    const int c1 = __popcll(b1);
    const int cX = __popcll(bX);
    unsigned long long below = (1ull << lane) - 1ull;
    if (act_c) {
        int idx = (np_c == 1) ? __popcll(b1 & below) : c1 + __popcll(bX & below);
        float4 e;
        e.x = nmn_c; e.y = inv_c;
        e.z = __int_as_float(pos_c);
        e.w = __int_as_float(w * CHE4 + lane * 49);   // channel == lane
        list[w * NC + idx] = e;
    }
    // no barrier: each wave reads only its own list segment (in-order LDS)

    // ---- phase 2: stream h; static chunks, all loads issued up-front ----
    const float4* hb4 = (const float4*)(h + (size_t)b0 * CHE);
    const int  lane49 = lane < 48 ? lane : 48;
    const bool lv     = (lane < 49);
    const int  pix0   = lane49 * 4;
    const int  rr0    = pix0 / 14;
    const int  cc0    = pix0 - 14 * rr0;       // even: 0..12
    const bool wrap   = (cc0 == 12);
    const int  ccB    = wrap ? 0 : cc0 + 2;
    const int  lbase  = w * NC;
    float acc = 0.f;

    auto chunk7 = [&](int base, int cnt) {     // np == 1 fast path
        float4 mv[7], hv[7];
        #pragma unroll
        for (int j = 0; j < 7; j++) {
            int ee = base + j;
            mv[j] = list[lbase + (ee < cnt ? ee : cnt - 1)];
        }
        #pragma unroll
        for (int j = 0; j < 7; j++)
            hv[j] = hb4[__float_as_int(mv[j].w) + lane49];   // 7 independent loads
        #pragma unroll
        for (int j = 0; j < 7; j++) {
            int   p   = __float_as_int(mv[j].z);
            float nmn = mv[j].x, inv = mv[j].y;
            int y = p & 15, x = (p >> 4) & 15;
            const float* ry = &gs[y * GSTR];
            const float* rx = &gs[x * GSTR];
            float wy0  = ry[rr0], wy1 = ry[rr0 + 1];
            float wxA0 = rx[cc0], wxA1 = rx[cc0 + 1];
            float wxB0 = rx[ccB], wxB1 = rx[ccB + 1];
            float wyC  = wrap ? wy1 : wy0;
            float d0 = hv[j].x - fmaf(wy0 * wxA0, inv, nmn);
            float d1 = hv[j].y - fmaf(wy0 * wxA1, inv, nmn);
            float d2 = hv[j].z - fmaf(wyC * wxB0, inv, nmn);
            float d3 = hv[j].w - fmaf(wyC * wxB1, inv, nmn);
            float s  = fmaf(d0, d0, fmaf(d1, d1, fmaf(d2, d2, d3 * d3)));
            acc += ((base + j < cnt) && lv) ? s : 0.f;
        }
    };
    if (c1 > 0)  chunk7(0, c1);        // c1 <= 18 => <= 3 chunks, wave-uniform
    if (c1 > 7)  chunk7(7, c1);
    if (c1 > 14) chunk7(14, c1);

    const int cT = c1 + cX;
    if (cX > 0) {                      // np >= 2: padded 3-position formula, cX <= 4
        float4 mv[4], hv[4];
        #pragma unroll
        for (int j = 0; j < 4; j++) {
            int ee = c1 + j;
            mv[j] = list[lbase + (ee < cT ? ee : cT - 1)];
        }
        #pragma unroll
        for (int j = 0; j < 4; j++)
            hv[j] = hb4[__float_as_int(mv[j].w) + lane49];
        #pragma unroll
        for (int j = 0; j < 4; j++) {
            int   p   = __float_as_int(mv[j].z);
            float nmn = mv[j].x, inv = mv[j].y;
            float f0 = 0.f, f1 = 0.f, f2 = 0.f, f3 = 0.f;
            #pragma unroll
            for (int q = 0; q < 3; q++) {
                int y = (p >> (8 * q)) & 15, x = (p >> (8 * q + 4)) & 15;
                const float* ry = &gs[y * GSTR];
                const float* rx = &gs[x * GSTR];
                float wy0  = ry[rr0], wy1 = ry[rr0 + 1];
                float wxA0 = rx[cc0], wxA1 = rx[cc0 + 1];
                float wxB0 = rx[ccB], wxB1 = rx[ccB + 1];
                float wyC  = wrap ? wy1 : wy0;
                f0 = fmaf(wy0, wxA0, f0);
                f1 = fmaf(wy0, wxA1, f1);
                f2 = fmaf(wyC, wxB0, f2);
                f3 = fmaf(wyC, wxB1, f3);
            }
            float d0 = hv[j].x - fmaf(f0, inv, nmn);
            float d1 = hv[j].y - fmaf(f1, inv, nmn);
            float d2 = hv[j].z - fmaf(f2, inv, nmn);
            float d3 = hv[j].w - fmaf(f3, inv, nmn);
            float s  = fmaf(d0, d0, fmaf(d1, d1, fmaf(d2, d2, d3 * d3)));
            acc += ((c1 + j < cT) && lv) ? s : 0.f;
        }
    }

    // ---- reduce ----
    #pragma unroll
    for (int off = 32; off > 0; off >>= 1) acc += __shfl_down(acc, off);
    if (lane == 0) wred[w] = acc;
    __syncthreads();
    if (tid == 0) {
        float2 pr;
        pr.x = wred[0] + wred[1] + wred[2] + wred[3];
        pr.y = wvs[0] + wvs[1] + wvs[2] + wvs[3];
        partials[blockIdx.x] = pr;
    }
}

__global__ __launch_bounds__(1024) void finalize_kernel(
    const float2* __restrict__ partials, float* __restrict__ out)
{
    __shared__ float w1[16], w2[16];
    int tid = threadIdx.x;
    float s = 0.f, vs = 0.f;
    #pragma unroll
    for (int i = 0; i < NBLK / 1024; i++) {
        float2 p = partials[tid + i * 1024];
        s += p.x; vs += p.y;
    }
    #pragma unroll
    for (int off = 32; off > 0; off >>= 1) {
        s  += __shfl_down(s, off);
        vs += __shfl_down(vs, off);
    }
    if ((tid & 63) == 0) { w1[tid >> 6] = s; w2[tid >> 6] = vs; }
    __syncthreads();
    if (tid == 0) {
        float stot = 0.f, vtot = 0.f;
        #pragma unroll
        for (int q = 0; q < 16; q++) { stot += w1[q]; vtot += w2[q]; }
        out[0] = stot / (vtot * 0.5f);
    }
}

extern "C" void kernel_launch(void* const* d_in, const int* in_sizes, int n_in,
                              void* d_out, int out_size, void* d_ws, size_t ws_size,
                              hipStream_t stream) {
    // inputs: 0=os (UNUSED), 1=h [B,18,14,14] f32, 2=t [B,14,2] f32, 3=v [B,14,2] i32
    const float* h = (const float*)d_in[1];
    const float* t = (const float*)d_in[2];
    const int*   v = (const int*)d_in[3];
    float2* partials = (float2*)d_ws;   // NBLK float2

    mse_partial_kernel<<<NBLK, 256, 0, stream>>>(h, t, v, partials);
    finalize_kernel<<<1, 1024, 0, stream>>>(partials, (float*)d_out);
}